// Round 12
// baseline (488.458 us; speedup 1.0000x reference)
//
#include <hip/hip_runtime.h>
#include <math.h>

#define NF 4096
#define NC 2048
#define BUF 1024
#define THREADS 512
#define NBANDS 2049
#define R2C 0.70710678118654752f

// LDS bank swizzle (empirically proven r6/r9): bijective on [0,2048)
__device__ __forceinline__ int SW(int i) { return i ^ (i >> 2) ^ (i >> 6); }

// digit-reversed position after DIF stages m=512,128,32,8,2 (final r2 folded)
__device__ __forceinline__ int posrev10(int j) {
  return ((j & 3) << 9) | (((j >> 2) & 3) << 7) | (((j >> 4) & 3) << 5) |
         (((j >> 6) & 3) << 3) | (((j >> 8) & 3) << 1);
}

struct Smem {
  alignas(16) float xs[BUF];            // 4096 B
  alignas(16) float zre[7][NC];         // 57344 B
  alignas(16) float zim[7][NC];         // 57344 B
  unsigned short P[6][2050];            // 24600 B  (bf16 power buffers)
  unsigned short S2[4][2050];           // 16400 B  (bf16 lvl2-min buffers)
};                                      // 159784 B -> 1 block/CU

struct Lane {
  float cl, sl;     // cos,sin(pi*lam/1024)
  float co, so;     // cos,sin(pi*(2lam+1)/2048)
  float2 A7;        // exp(-2pi i lam/512)      stage m=128 twiddle base
  float2 T5;        // exp(-2pi i (lam&31)/128) stage m=32
  float2 T3;        // exp(-2pi i (lam&7)/32)   stage m=8
  float2 Ub;        // exp(-pi i lam/2048)      unpack base
};

__device__ __forceinline__ float2 cmul(float2 a, float2 b) {
  return make_float2(a.x * b.x - a.y * b.y, a.x * b.y + a.y * b.x);
}
__device__ __forceinline__ float2 csq(float2 a) {
  return make_float2(a.x * a.x - a.y * a.y, 2.0f * a.x * a.y);
}
__device__ __forceinline__ unsigned short f2bf(float f) {
  unsigned u = __float_as_uint(f);
  return (unsigned short)((u + 0x7FFFu + ((u >> 16) & 1u)) >> 16);
}
__device__ __forceinline__ float bf2f(unsigned short h) {
  return __uint_as_float(((unsigned)h) << 16);
}

template <int L>
__device__ __forceinline__ float cheb(float c) {
  #pragma unroll
  for (int i = 0; i < L; ++i) c = 2.0f * c * c - 1.0f;
  return c;
}

// Fused pack + pruned first radix-4 stage (span 512): only tap3 nonzero.
// Per-wave: lane lam handles n = lam + 64q, q=0..7.
template <int L>
__device__ __forceinline__ void fs1(float* __restrict__ re, float* __restrict__ im,
                                    const float* __restrict__ xs, const Lane& ln, int off) {
  const int lam = threadIdx.x & 63;
  constexpr int M = NF >> L;
  constexpr float ws = (float)(1 << L) * (0.5f / 1024.0f);
  const int lo = 512 - (min(off, M) >> 1);
  const float CQ[8] = {1.0f, 0.980785280403230f, 0.923879532511287f, 0.831469612302545f,
                       0.707106781186548f, 0.555570233019602f, 0.382683432365090f, 0.195090322016128f};
  const float SQ[8] = {0.0f, 0.195090322016128f, 0.382683432365090f, 0.555570233019602f,
                       0.707106781186548f, 0.831469612302545f, 0.923879532511287f, 0.980785280403230f};
  #pragma unroll
  for (int q = 0; q < 8; ++q) {
    const int n = lam + 64 * q;
    // angle addition: cos/sin(pi*n/1024) from lane base + per-q constants
    const float cn = ln.cl * CQ[q] - ln.sl * SQ[q];
    const float sn = ln.sl * CQ[q] + ln.cl * SQ[q];
    const float son = ln.so * CQ[q] + ln.co * SQ[q];   // sin(pi(2n+1)/2048)
    float dr = 0.0f, di = 0.0f;
    if (n >= lo) {
      const int idx = 2 * n + off - 1024;
      const float2 xv = *(const float2*)&xs[idx];
      dr = ws * (1.0f - cheb<L>(sn)) * xv.x;     // cos at even sample = sin(pi n/1024)
      di = ws * (1.0f - cheb<L>(son)) * xv.y;
    }
    const float2 W = make_float2(cn, -sn);       // exp(-pi i n/1024)
    const float2 W2 = csq(W);
    const float2 W3 = cmul(W, W2);
    const int p0 = SW(n), p1 = SW(n + 512), p2 = SW(n + 1024), p3 = SW(n + 1536);
    re[p0] = dr;                       im[p0] = di;
    re[p1] = -di * W.x - dr * W.y;     im[p1] = -di * W.y + dr * W.x;     // (i d) W
    re[p2] = -(dr * W2.x - di * W2.y); im[p2] = -(dr * W2.y + di * W2.x); // -d W^2
    re[p3] =  di * W3.x + dr * W3.y;   im[p3] =  di * W3.y - dr * W3.x;   // (-i d) W^3
  }
}

__device__ __forceinline__ void fs1d(int L, float* re, float* im,
                                     const float* xs, const Lane& ln, int off) {
  if (L == 0)      fs1<0>(re, im, xs, ln, off);
  else if (L == 1) fs1<1>(re, im, xs, ln, off);
  else if (L == 2) fs1<2>(re, im, xs, ln, off);
  else             fs1<3>(re, im, xs, ln, off);
}

__device__ __forceinline__ void bfly4(float* __restrict__ re, float* __restrict__ im,
                                      int i0, int i1, int i2, int i3,
                                      float2 W, float2 W2, float2 W3) {
  float ar = re[i0], ai = im[i0];
  float br = re[i1], bi = im[i1];
  float cr = re[i2], ci = im[i2];
  float dr = re[i3], di = im[i3];
  float t0r = ar + cr, t0i = ai + ci;
  float t1r = ar - cr, t1i = ai - ci;
  float t2r = br + dr, t2i = bi + di;
  float t3r = br - dr, t3i = bi - di;
  re[i0] = t0r + t2r; im[i0] = t0i + t2i;
  float y1r = t1r + t3i, y1i = t1i - t3r;
  re[i1] = y1r * W.x - y1i * W.y;  im[i1] = y1r * W.y + y1i * W.x;
  float y2r = t0r - t2r, y2i = t0i - t2i;
  re[i2] = y2r * W2.x - y2i * W2.y; im[i2] = y2r * W2.y + y2i * W2.x;
  float y3r = t1r - t3i, y3i = t1i + t3r;
  re[i3] = y3r * W3.x - y3i * W3.y; im[i3] = y3r * W3.y + y3i * W3.x;
}

// Wave-internal ordering of LDS ops (lockstep wave64 + lgkmcnt drain).
__device__ __forceinline__ void wfence() { __threadfence_block(); }

// Remaining 4 radix-4 stages, entirely within one wave on its own z-slot.
__device__ __forceinline__ void stages(float* __restrict__ re, float* __restrict__ im,
                                       const Lane& ln) {
  const int lam = threadIdx.x & 63;
  wfence();
  { // m=128: twiddle pos = lam (+64 for odd q)
    const float2 Wa = ln.A7, Wb = cmul(Wa, make_float2(R2C, -R2C));
    const float2 Wa2 = csq(Wa), Wb2 = csq(Wb);
    const float2 Wa3 = cmul(Wa, Wa2), Wb3 = cmul(Wb, Wb2);
    #pragma unroll
    for (int q = 0; q < 8; ++q) {
      const int j = lam + 64 * q;
      const int base = ((j >> 7) << 9) | (j & 127);
      if (q & 1) bfly4(re, im, SW(base), SW(base + 128), SW(base + 256), SW(base + 384), Wb, Wb2, Wb3);
      else       bfly4(re, im, SW(base), SW(base + 128), SW(base + 256), SW(base + 384), Wa, Wa2, Wa3);
    }
  }
  wfence();
  { // m=32: pos = lam&31 (same for all q)
    const float2 W = ln.T5, W2 = csq(W), W3 = cmul(W, W2);
    #pragma unroll
    for (int q = 0; q < 8; ++q) {
      const int j = lam + 64 * q;
      const int base = ((j >> 5) << 7) | (j & 31);
      bfly4(re, im, SW(base), SW(base + 32), SW(base + 64), SW(base + 96), W, W2, W3);
    }
  }
  wfence();
  { // m=8: pos = lam&7
    const float2 W = ln.T3, W2 = csq(W), W3 = cmul(W, W2);
    #pragma unroll
    for (int q = 0; q < 8; ++q) {
      const int j = lam + 64 * q;
      const int base = ((j >> 3) << 5) | (j & 7);
      bfly4(re, im, SW(base), SW(base + 8), SW(base + 16), SW(base + 24), W, W2, W3);
    }
  }
  wfence();
  { // m=2: pos = lam&1 (constant twiddles)
    const bool o = (lam & 1);
    const float2 W  = o ? make_float2(R2C, -R2C)  : make_float2(1.0f, 0.0f);
    const float2 W2 = o ? make_float2(0.0f, -1.0f) : make_float2(1.0f, 0.0f);
    const float2 W3 = o ? make_float2(-R2C, -R2C) : make_float2(1.0f, 0.0f);
    #pragma unroll
    for (int q = 0; q < 8; ++q) {
      const int j = lam + 64 * q;
      const int base = ((j >> 1) << 3) | (j & 1);
      bfly4(re, im, SW(base), SW(base + 2), SW(base + 4), SW(base + 6), W, W2, W3);
    }
  }
  wfence();
}

// rfft pair unpack (r9 machinery, verbatim math)
__device__ __forceinline__ void pair_powers(const float* __restrict__ re,
                                            const float* __restrict__ im,
                                            int kp, float2 U, float& pp, float& pm) {
  const int k1 = kp & (NC - 1);
  const int k2 = (NC - kp) & (NC - 1);
  const int q1 = SW(posrev10(k1 & 1023));
  const int q2 = SW(posrev10(k2 & 1023));
  const float s1 = (k1 & 1024) ? -1.0f : 1.0f;
  const float s2 = (k2 & 1024) ? -1.0f : 1.0f;
  const float2 vr1 = *(const float2*)&re[q1 & ~1];
  const float2 vi1 = *(const float2*)&im[q1 & ~1];
  const float2 vr2 = *(const float2*)&re[q2 & ~1];
  const float2 vi2 = *(const float2*)&im[q2 & ~1];
  const bool o1 = (q1 & 1), o2 = (q2 & 1);
  const float zkr = o1 ? (vr1.y + s1 * vr1.x) : (vr1.x + s1 * vr1.y);
  const float zki = o1 ? (vi1.y + s1 * vi1.x) : (vi1.x + s1 * vi1.y);
  const float zmr = o2 ? (vr2.y + s2 * vr2.x) : (vr2.x + s2 * vr2.y);
  const float zmi = o2 ? (vi2.y + s2 * vi2.x) : (vi2.x + s2 * vi2.y);
  const float Ex = 0.5f * (zkr + zmr), Ey = 0.5f * (zki - zmi);
  const float Ox = 0.5f * (zki + zmi), Oy = -0.5f * (zkr - zmr);
  const float Vx = U.x * Ox - U.y * Oy, Vy = U.x * Oy + U.y * Ox;
  const float ax = Ex + Vx, ay = Ey + Vy;
  const float bx = Ex - Vx, by = Ey - Vy;
  pp = ax * ax + ay * ay;
  pm = bx * bx + by * by;
}

#define CS_TBL                                                                     \
  const float CSr[8] = {1.0f, 0.995184726672197f, 0.980785280403230f,              \
                        0.956940335732209f, 0.923879532511287f, 0.881921264348355f,\
                        0.831469612302545f, 0.773010453362737f};                   \
  const float CSi[8] = {0.0f, -0.0980171403295606f, -0.195090322016128f,           \
                        -0.290284677254462f, -0.382683432365090f,                  \
                        -0.471396736825998f, -0.555570233019602f, -0.634393284163645f};

// Full-wave unpack -> bf16 power buffer (bins t,2048-t,512+t,1536-t; +1024)
__device__ __forceinline__ void unpack_storeP(const float* re, const float* im,
                                              const Lane& ln, unsigned short* __restrict__ P) {
  const int lam = threadIdx.x & 63;
  CS_TBL
  #pragma unroll
  for (int s = 0; s < 8; ++s) {
    const int t = lam + 64 * s;
    const float2 U = cmul(ln.Ub, make_float2(CSr[s], CSi[s]));
    const float2 U1 = cmul(U, make_float2(R2C, -R2C));
    float pp, pm;
    pair_powers(re, im, t, U, pp, pm);
    P[t] = f2bf(fminf(pp, 1.0e6f));
    P[2048 - t] = f2bf(fminf(pm, 1.0e6f));
    pair_powers(re, im, 512 + t, U1, pp, pm);
    P[512 + t] = f2bf(fminf(pp, 1.0e6f));
    P[1536 - t] = f2bf(fminf(pm, 1.0e6f));
  }
  if (lam == 0) {
    const float zr = re[0] - re[1], zi = im[0] - im[1];
    P[1024] = f2bf(fminf(zr * zr + zi * zi, 1.0e6f));
  }
}

__device__ __forceinline__ void emit(float* __restrict__ outb,
                                     const unsigned short* __restrict__ S2n,
                                     int col, int b, float p) {
  const float m = fminf(bf2f(S2n[b]), p);
  outb[(size_t)b * 8 + col] = 10.0f * log10f(fmaxf(m, 1.0e-10f));
}

// Leaf (lvl3) unpack: min with S2 node, dB, direct global store.
__device__ __forceinline__ void unpack_out(const float* re, const float* im, const Lane& ln,
                                           const unsigned short* __restrict__ S2n,
                                           float* __restrict__ outb, int col) {
  const int lam = threadIdx.x & 63;
  CS_TBL
  #pragma unroll
  for (int s = 0; s < 8; ++s) {
    const int t = lam + 64 * s;
    const float2 U = cmul(ln.Ub, make_float2(CSr[s], CSi[s]));
    const float2 U1 = cmul(U, make_float2(R2C, -R2C));
    float pp, pm;
    pair_powers(re, im, t, U, pp, pm);
    emit(outb, S2n, col, t, pp);
    emit(outb, S2n, col, 2048 - t, pm);
    pair_powers(re, im, 512 + t, U1, pp, pm);
    emit(outb, S2n, col, 512 + t, pp);
    emit(outb, S2n, col, 1536 - t, pm);
  }
  if (lam == 0) {
    const float zr = re[0] - re[1], zi = im[0] - im[1];
    emit(outb, S2n, col, 1024, zr * zr + zi * zi);
  }
}

// S2_j = min(l0, l1_{j/2}, l2_j): P idx 0=l0,1=l1_0,2=l1_1,3..5=l2_0..2
__device__ __forceinline__ void combineA(Smem& sm) {
  for (int k = threadIdx.x; k < NBANDS; k += THREADS) {
    const float p0 = bf2f(sm.P[0][k]);
    const float a = fminf(p0, bf2f(sm.P[1][k]));
    const float b = fminf(p0, bf2f(sm.P[2][k]));
    sm.S2[0][k] = f2bf(fminf(a, bf2f(sm.P[3][k])));
    sm.S2[1][k] = f2bf(fminf(a, bf2f(sm.P[4][k])));
    sm.S2[2][k] = f2bf(fminf(b, bf2f(sm.P[5][k])));
  }
}
// S2_3 = min(l0, l1_1, l2_3); l2_3 was written into P[1]
__device__ __forceinline__ void combineB(Smem& sm) {
  for (int k = threadIdx.x; k < NBANDS; k += THREADS) {
    sm.S2[3][k] = f2bf(fminf(fminf(bf2f(sm.P[0][k]), bf2f(sm.P[2][k])), bf2f(sm.P[1][k])));
  }
}

// round-table code: act | L<<1 | off128<<3 | kindP<<7 | idx<<8 | col<<11
#define RCODE(act, L, o, kp, idx, col) \
  ((act) | ((L) << 1) | ((o) << 3) | ((kp) << 7) | ((idx) << 8) | ((col) << 11))

__global__ __launch_bounds__(THREADS) void spec_kernel(const float* __restrict__ x,
                                                       float* __restrict__ out) {
  __shared__ Smem sm;
  const int tid = threadIdx.x;
  const int lam = tid & 63;
  const int w = tid >> 6;
  const int b = blockIdx.x;
  for (int i = tid; i < BUF; i += THREADS) sm.xs[i] = x[(size_t)b * BUF + i];
  Lane ln;
  {
    float sn, cs;
    sincospif((float)lam * (1.0f / 1024.0f), &sn, &cs);           ln.cl = cs; ln.sl = sn;
    sincospif((float)(2 * lam + 1) * (1.0f / 2048.0f), &sn, &cs); ln.co = cs; ln.so = sn;
    sincospif((float)lam * (1.0f / 256.0f), &sn, &cs);            ln.A7 = make_float2(cs, -sn);
    sincospif((float)(lam & 31) * (1.0f / 64.0f), &sn, &cs);      ln.T5 = make_float2(cs, -sn);
    sincospif((float)(lam & 7) * (1.0f / 16.0f), &sn, &cs);       ln.T3 = make_float2(cs, -sn);
    sincospif((float)lam * (1.0f / 2048.0f), &sn, &cs);           ln.Ub = make_float2(cs, -sn);
  }
  float* outb = out + (size_t)b * (NBANDS * 8);

  // rounds: A = {l0,l1_0,l1_1,l2_0,l2_1,l2_2}; B = {l2_3, l3_0..l3_5}; C = {l3_6,l3_7}
  static const int RT[3][8] = {
    { RCODE(1,0,8,1,0,0), RCODE(1,1,4,1,1,0), RCODE(1,1,8,1,2,0),
      RCODE(1,2,2,1,3,0), RCODE(1,2,4,1,4,0), RCODE(1,2,6,1,5,0), 0, 0 },
    { RCODE(1,2,8,1,1,0), RCODE(1,3,1,0,0,0), RCODE(1,3,2,0,0,1),
      RCODE(1,3,3,0,1,2), RCODE(1,3,4,0,1,3), RCODE(1,3,5,0,2,4),
      RCODE(1,3,6,0,2,5), 0 },
    { RCODE(1,3,7,0,3,6), RCODE(1,3,8,0,3,7), 0, 0, 0, 0, 0, 0 },
  };

  __syncthreads();                               // xs ready
  #pragma unroll 1
  for (int r = 0; r < 3; ++r) {
    const int code = RT[r][w];                   // wave-uniform
    if (code) {
      float* re = sm.zre[w];
      float* im = sm.zim[w];
      const int L = (code >> 1) & 3;
      const int off = ((code >> 3) & 15) << 7;
      fs1d(L, re, im, sm.xs, ln, off);
      stages(re, im, ln);                        // barrier-free, wave-internal
      if (code & (1 << 7)) unpack_storeP(re, im, ln, sm.P[(code >> 8) & 7]);
      else unpack_out(re, im, ln, sm.S2[(code >> 8) & 7], outb, (code >> 11) & 7);
    }
    __syncthreads();
    if (r == 0) { combineA(sm); __syncthreads(); }
    else if (r == 1) { combineB(sm); __syncthreads(); }
  }
}

extern "C" void kernel_launch(void* const* d_in, const int* in_sizes, int n_in,
                              void* d_out, int out_size, void* d_ws, size_t ws_size,
                              hipStream_t stream) {
  const float* x = (const float*)d_in[0];
  float* out = (float*)d_out;
  const int B = in_sizes[0] / BUF;
  hipLaunchKernelGGL(spec_kernel, dim3(B), dim3(THREADS), 0, stream, x, out);
}

// Round 14
// 150.399 us; speedup vs baseline: 3.2477x; 3.2477x over previous
//
#include <hip/hip_runtime.h>
#include <hip/hip_fp16.h>
#include <math.h>

#define NBANDS 2049
#define NF 4096      // real frame size
#define NC 2048      // complex FFT size (rfft via packed complex)
#define BUF 1024     // input samples per batch row
#define THREADS 512
#define R2C 0.70710678118654752f

// LDS bank swizzle (empirically proven r6/r9: 1.9M conflicts)
__device__ __forceinline__ int SW(int i) { return i ^ (i >> 2) ^ (i >> 6); }

// digit-reversed position after 5 radix-4 stages (final radix-2 folded out);
// output is always even
__device__ __forceinline__ int posrev10(int j) {
  return ((j & 3) << 9) | (((j >> 2) & 3) << 7) | (((j >> 4) & 3) << 5) |
         (((j >> 6) & 3) << 3) | (((j >> 8) & 3) << 1);
}

struct Smem {
  alignas(16) float xs[BUF];       // 4 KB
  alignas(16) float zre[3][NC];    // 24 KB
  alignas(16) float zim[3][NC];    // 24 KB
};                                 // 52.5 KB -> 3 blocks/CU if VGPR <= ~85

struct State {
  float2 W[4];                   // stage twiddles m=512(also window base),128,32,8
  float2 Ub;                     // exp(-pi*i*tid/2048)
  float so;                      // sin(pi*(2*tid+1)/2048) (odd window base)
  float s1a[5], s1b[5];          // running mins after lvl1 (two subtrees)
  float s2a[5], s2b[5];          // running mins after lvl2 (two live nodes)
  __half2 oh[4][5];              // dB output columns, f16-packed in registers
};

__device__ __forceinline__ float2 cmul(float2 a, float2 b) {
  return make_float2(a.x * b.x - a.y * b.y, a.x * b.y + a.y * b.x);
}

// Chebyshev cos-doubling: cos(t) -> cos(2^L * t)
template <int L>
__device__ __forceinline__ float cheb(float c) {
  #pragma unroll
  for (int i = 0; i < L; ++i) c = 2.0f * c * c - 1.0f;
  return c;
}

// Fused pack + pruned first radix-4 stage (span 512): only tap3 nonzero.
// y = {d, i*d*W, -d*W^2, -i*d*W^3}, d = windowed sample pair from xs.
template <int L>
__device__ __forceinline__ void fused_s1(float* __restrict__ re, float* __restrict__ im,
                                         const Smem& sm, const State& st, int off) {
  const int n = threadIdx.x;
  constexpr int M = NF >> L;
  constexpr float ws = (float)(1 << L) * (0.5f / 1024.0f);
  const int lo = 512 - (min(off, M) >> 1);
  float dr = 0.0f, di = 0.0f;
  if (n >= lo) {
    const int idx = 2 * n + off - 1024;          // even, in [0, off)
    const float2 xv = *(const float2*)&sm.xs[idx];
    const float cE = cheb<L>(-st.W[0].y);        // cos at even sample
    const float cO = cheb<L>(st.so);             // cos at odd sample
    dr = ws * (1.0f - cE) * xv.x;
    di = ws * (1.0f - cO) * xv.y;
  }
  const float2 W = st.W[0];
  const float2 W2 = make_float2(W.x * W.x - W.y * W.y, 2.0f * W.x * W.y);
  const float2 W3 = cmul(W, W2);
  const int p0 = SW(n), p1 = SW(n + 512), p2 = SW(n + 1024), p3 = SW(n + 1536);
  re[p0] = dr;                       im[p0] = di;
  re[p1] = -di * W.x - dr * W.y;     im[p1] = -di * W.y + dr * W.x;     // (i d) W
  re[p2] = -(dr * W2.x - di * W2.y); im[p2] = -(dr * W2.y + di * W2.x); // -d W^2
  re[p3] =  di * W3.x + dr * W3.y;   im[p3] =  di * W3.y - dr * W3.x;   // (-i d) W^3
}

__device__ __forceinline__ void bfly4(float* __restrict__ re, float* __restrict__ im,
                                      int i0, int i1, int i2, int i3,
                                      float2 W, float2 W2, float2 W3) {
  float ar = re[i0], ai = im[i0];
  float br = re[i1], bi = im[i1];
  float cr = re[i2], ci = im[i2];
  float dr = re[i3], di = im[i3];
  float t0r = ar + cr, t0i = ai + ci;
  float t1r = ar - cr, t1i = ai - ci;
  float t2r = br + dr, t2i = bi + di;
  float t3r = br - dr, t3i = bi - di;
  re[i0] = t0r + t2r; im[i0] = t0i + t2i;
  float y1r = t1r + t3i, y1i = t1i - t3r;                  // (t1 - i*t3)
  re[i1] = y1r * W.x - y1i * W.y;  im[i1] = y1r * W.y + y1i * W.x;
  float y2r = t0r - t2r, y2i = t0i - t2i;
  re[i2] = y2r * W2.x - y2i * W2.y; im[i2] = y2r * W2.y + y2i * W2.x;
  float y3r = t1r - t3i, y3i = t1i + t3r;                  // (t1 + i*t3)
  re[i3] = y3r * W3.x - y3i * W3.y; im[i3] = y3r * W3.y + y3i * W3.x;
}

template <int LM, int NFR>
__device__ __forceinline__ void radix4p(Smem& sm, float2 W) {
  const int j = threadIdx.x;
  const int m = 1 << LM;
  const int base = ((j >> LM) << (LM + 2)) | (j & (m - 1));
  const int i0 = SW(base), i1 = SW(base + m), i2 = SW(base + 2 * m), i3 = SW(base + 3 * m);
  float2 W2 = make_float2(W.x * W.x - W.y * W.y, 2.0f * W.x * W.y);
  float2 W3 = cmul(W, W2);
  #pragma unroll
  for (int f = 0; f < NFR; ++f)
    bfly4(sm.zre[f], sm.zim[f], i0, i1, i2, i3, W, W2, W3);
}

// Shared-read pair unpack: bins kp and 2048-kp read the same Z values.
// {q, q^1} is an adjacent aligned float pair -> one b64 LDS read each.
__device__ __forceinline__ void pair_powers(const float* __restrict__ re,
                                            const float* __restrict__ im,
                                            int kp, float2 U, float& pp, float& pm) {
  const int k1 = kp & (NC - 1);
  const int k2 = (NC - kp) & (NC - 1);
  const int q1 = SW(posrev10(k1 & 1023));
  const int q2 = SW(posrev10(k2 & 1023));
  const float s1 = (k1 & 1024) ? -1.0f : 1.0f;
  const float s2 = (k2 & 1024) ? -1.0f : 1.0f;
  const float2 vr1 = *(const float2*)&re[q1 & ~1];
  const float2 vi1 = *(const float2*)&im[q1 & ~1];
  const float2 vr2 = *(const float2*)&re[q2 & ~1];
  const float2 vi2 = *(const float2*)&im[q2 & ~1];
  const bool o1 = (q1 & 1), o2 = (q2 & 1);
  const float zkr = o1 ? (vr1.y + s1 * vr1.x) : (vr1.x + s1 * vr1.y);
  const float zki = o1 ? (vi1.y + s1 * vi1.x) : (vi1.x + s1 * vi1.y);
  const float zmr = o2 ? (vr2.y + s2 * vr2.x) : (vr2.x + s2 * vr2.y);
  const float zmi = o2 ? (vi2.y + s2 * vi2.x) : (vi2.x + s2 * vi2.y);
  const float Ex = 0.5f * (zkr + zmr), Ey = 0.5f * (zki - zmi);
  const float Ox = 0.5f * (zki + zmi), Oy = -0.5f * (zkr - zmr);
  const float Vx = U.x * Ox - U.y * Oy, Vy = U.x * Oy + U.y * Ox;
  const float ax = Ex + Vx, ay = Ey + Vy;
  const float bx = Ex - Vx, by = Ey - Vy;
  pp = ax * ax + ay * ay;
  pm = bx * bx + by * by;
}

// ACT: 0 s1a=min(p,1e6); 1 s1b=min(p,1e6); 2 lvl0 fold into s1a&s1b;
//      3 s2a=min(s1a,p); 4 s2b=min(s1a,p); 5 s2a=min(s1b,p); 6 s2b=min(s1b,p);
//      7 o[COL]=dB(min(s2a,p)); 8 o[COL]=dB(min(s2b,p))
template <int ACT, int COL, int SLOT>
__device__ __forceinline__ void act(State& st, float p) {
  if constexpr (ACT == 0)      st.s1a[SLOT] = fminf(p, 1.0e6f);
  else if constexpr (ACT == 1) st.s1b[SLOT] = fminf(p, 1.0e6f);
  else if constexpr (ACT == 2) { st.s1a[SLOT] = fminf(st.s1a[SLOT], p); st.s1b[SLOT] = fminf(st.s1b[SLOT], p); }
  else if constexpr (ACT == 3) st.s2a[SLOT] = fminf(st.s1a[SLOT], p);
  else if constexpr (ACT == 4) st.s2b[SLOT] = fminf(st.s1a[SLOT], p);
  else if constexpr (ACT == 5) st.s2a[SLOT] = fminf(st.s1b[SLOT], p);
  else if constexpr (ACT == 6) st.s2b[SLOT] = fminf(st.s1b[SLOT], p);
  else {
    const float base = (ACT == 7) ? st.s2a[SLOT] : st.s2b[SLOT];
    const float db = 10.0f * log10f(fmaxf(fminf(base, p), 1.0e-10f));
    if constexpr (COL & 1) st.oh[COL >> 1][SLOT].y = __float2half_rn(db);
    else                   st.oh[COL >> 1][SLOT].x = __float2half_rn(db);
  }
}

template <int ACT, int COL>
__device__ __forceinline__ void unpack_frame(const float* __restrict__ re,
                                             const float* __restrict__ im,
                                             State& st) {
  const int t = threadIdx.x;
  const float2 U1 = cmul(st.Ub, make_float2(R2C, -R2C));
  float pp, pm;
  pair_powers(re, im, t, st.Ub, pp, pm);
  act<ACT, COL, 0>(st, pp);
  act<ACT, COL, 1>(st, pm);
  pair_powers(re, im, 512 + t, U1, pp, pm);
  act<ACT, COL, 2>(st, pp);
  act<ACT, COL, 3>(st, pm);
  if (t == 0) {
    // bin 1024: Z[1024] = D[0] - D[1]
    const float zr = re[0] - re[1];
    const float zi = im[0] - im[1];
    act<ACT, COL, 4>(st, zr * zr + zi * zi);
  }
}

// One pass = three windowed frames FFT'd together, unpacked, min-chain applied.
template <int LA, int AA, int CA, int LB, int AB, int CB, int LC, int AC, int CC, int NFR>
__device__ __forceinline__ void pass(Smem& sm, State& st, int offA, int offB, int offC) {
  __syncthreads();                          // prior pass done reading z arrays
  fused_s1<LA>(sm.zre[0], sm.zim[0], sm, st, offA);
  if constexpr (NFR >= 2) fused_s1<LB>(sm.zre[1], sm.zim[1], sm, st, offB);
  if constexpr (NFR >= 3) fused_s1<LC>(sm.zre[2], sm.zim[2], sm, st, offC);
  __syncthreads(); radix4p<7, NFR>(sm, st.W[1]);
  __syncthreads(); radix4p<5, NFR>(sm, st.W[2]);
  __syncthreads(); radix4p<3, NFR>(sm, st.W[3]);
  __syncthreads();
  {
    const float2 W4 = (threadIdx.x & 1) ? make_float2(R2C, -R2C) : make_float2(1.0f, 0.0f);
    radix4p<1, NFR>(sm, W4);
  }
  __syncthreads();
  unpack_frame<AA, CA>(sm.zre[0], sm.zim[0], st);
  if constexpr (NFR >= 2) unpack_frame<AB, CB>(sm.zre[1], sm.zim[1], st);
  if constexpr (NFR >= 3) unpack_frame<AC, CC>(sm.zre[2], sm.zim[2], st);
}

// Thread t owns bands {t, 2048-t, 512+t, 1536-t, (1024 if t==0)}; 32B per band.
__device__ __forceinline__ void store_all(const State& st, float* __restrict__ outb) {
  const int t = threadIdx.x;
  #pragma unroll
  for (int sl = 0; sl < 5; ++sl) {
    if (sl < 4 || t == 0) {
      const int band = (sl == 0) ? t : (sl == 1) ? 2048 - t
                     : (sl == 2) ? 512 + t : (sl == 3) ? 1536 - t : 1024;
      float* bp = outb + (size_t)band * 8;
      *(float4*)(bp)     = make_float4(__half2float(st.oh[0][sl].x), __half2float(st.oh[0][sl].y),
                                       __half2float(st.oh[1][sl].x), __half2float(st.oh[1][sl].y));
      *(float4*)(bp + 4) = make_float4(__half2float(st.oh[2][sl].x), __half2float(st.oh[2][sl].y),
                                       __half2float(st.oh[3][sl].x), __half2float(st.oh[3][sl].y));
    }
  }
}

__global__ __launch_bounds__(THREADS, 3) void spec_kernel(const float* __restrict__ x,
                                                          float* __restrict__ out) {
  __shared__ Smem sm;
  State st;
  const int tid = threadIdx.x;
  const int b = blockIdx.x;
  const float* xb = x + (size_t)b * BUF;
  #pragma unroll
  for (int i = tid; i < BUF; i += THREADS) sm.xs[i] = xb[i];
  {
    float sn, cs;
    sincospif((float)tid * (1.0f / 1024.0f), &sn, &cs);         st.W[0] = make_float2(cs, -sn);
    sincospif((float)(tid & 127) * (1.0f / 256.0f), &sn, &cs);  st.W[1] = make_float2(cs, -sn);
    sincospif((float)(tid & 31) * (1.0f / 64.0f), &sn, &cs);    st.W[2] = make_float2(cs, -sn);
    sincospif((float)(tid & 7) * (1.0f / 16.0f), &sn, &cs);     st.W[3] = make_float2(cs, -sn);
    sincospif((float)tid * (1.0f / 2048.0f), &sn, &cs);         st.Ub = make_float2(cs, -sn);
    sincospif((float)(2 * tid + 1) * (1.0f / 2048.0f), &sn, &cs); st.so = sn;
  }
  float* outb = out + (size_t)b * (NBANDS * 8);

  // Frames: lvl0 off=1024; lvl1 off=512*(i+1); lvl2 off=256*(i+1); lvl3 off=128*(i+1)
  // 15 frames in 5 passes of 3 (schedule verified r9):
  pass<1, 0, 0,  1, 1, 0,  0, 2, 0, 3>(sm, st, 512, 1024, 1024);  // s1a=l1_0; s1b=l1_1; fold l0
  pass<2, 3, 0,  2, 4, 0,  3, 7, 0, 3>(sm, st, 256, 512, 128);    // s2a=min(s1a,l2_0); s2b=min(s1a,l2_1); o0
  pass<3, 7, 1,  3, 8, 2,  3, 8, 3, 3>(sm, st, 256, 384, 512);    // o1(s2a); o2(s2b); o3(s2b)
  pass<2, 5, 0,  2, 6, 0,  3, 7, 4, 3>(sm, st, 768, 1024, 640);   // s2a=min(s1b,l2_2); s2b=min(s1b,l2_3); o4
  pass<3, 7, 5,  3, 8, 6,  3, 8, 7, 3>(sm, st, 768, 896, 1024);   // o5(s2a); o6(s2b); o7(s2b)
  store_all(st, outb);
}

extern "C" void kernel_launch(void* const* d_in, const int* in_sizes, int n_in,
                              void* d_out, int out_size, void* d_ws, size_t ws_size,
                              hipStream_t stream) {
  const float* x = (const float*)d_in[0];
  float* out = (float*)d_out;
  const int B = in_sizes[0] / BUF;
  hipLaunchKernelGGL(spec_kernel, dim3(B), dim3(THREADS), 0, stream, x, out);
}

// Round 18
// 112.634 us; speedup vs baseline: 4.3367x; 1.3353x over previous
//
#include <hip/hip_runtime.h>
#include <hip/hip_fp16.h>
#include <math.h>

#define NBANDS 2049
#define NF 4096
#define NC 2048
#define BUF 1024
#define THREADS 512
#define R2C 0.70710678118654752f

// LDS bank swizzle (empirically proven r6/r9/r12: ~1.9M conflicts)
__device__ __forceinline__ int SW(int i) { return i ^ (i >> 2) ^ (i >> 6); }

// digit-reversed position after 5 radix-4 stages (final radix-2 folded out)
__device__ __forceinline__ int posrev10(int j) {
  return ((j & 3) << 9) | (((j >> 2) & 3) << 7) | (((j >> 4) & 3) << 5) |
         (((j >> 6) & 3) << 3) | (((j >> 8) & 3) << 1);
}

struct Smem {
  alignas(16) float xs[BUF];       // 4 KB
  alignas(16) float zre[8][NC];    // 64 KB
  alignas(16) float zim[8][NC];    // 64 KB
};                                 // 132 KB -> 1 block/CU (8 waves)

struct Lane {
  float cl, sl;     // cos,sin(pi*lam/1024)
  float co, so;     // cos,sin(pi*(2lam+1)/2048)
  float2 A7;        // exp(-2pi i lam/512)   stage m=128 twiddle base
  float2 T5;        // exp(-2pi i (lam&31)/128) stage m=32
  float2 T3;        // exp(-2pi i (lam&7)/32)   stage m=8
  float2 Ub;        // exp(-pi i tid/2048)   unpack base (thread-level)
};

__device__ __forceinline__ float2 cmul(float2 a, float2 b) {
  return make_float2(a.x * b.x - a.y * b.y, a.x * b.y + a.y * b.x);
}
__device__ __forceinline__ float2 csq(float2 a) {
  return make_float2(a.x * a.x - a.y * a.y, 2.0f * a.x * a.y);
}
__device__ __forceinline__ float dbv(float m) {
  return 10.0f * log10f(fmaxf(m, 1.0e-10f));
}

template <int L>
__device__ __forceinline__ float cheb(float c) {
  #pragma unroll
  for (int i = 0; i < L; ++i) c = 2.0f * c * c - 1.0f;
  return c;
}

// ---- r12-proven wave-autonomous FFT pipeline ----
// Fused pack + pruned first radix-4 stage (span 512): only tap3 nonzero.
// Lane lam handles n = lam + 64q, q=0..7.
template <int L>
__device__ __forceinline__ void fs1(float* __restrict__ re, float* __restrict__ im,
                                    const float* __restrict__ xs, const Lane& ln, int off) {
  const int lam = threadIdx.x & 63;
  constexpr int M = NF >> L;
  constexpr float ws = (float)(1 << L) * (0.5f / 1024.0f);
  const int lo = 512 - (min(off, M) >> 1);
  const float CQ[8] = {1.0f, 0.980785280403230f, 0.923879532511287f, 0.831469612302545f,
                       0.707106781186548f, 0.555570233019602f, 0.382683432365090f, 0.195090322016128f};
  const float SQ[8] = {0.0f, 0.195090322016128f, 0.382683432365090f, 0.555570233019602f,
                       0.707106781186548f, 0.831469612302545f, 0.923879532511287f, 0.980785280403230f};
  #pragma unroll
  for (int q = 0; q < 8; ++q) {
    const int n = lam + 64 * q;
    const float cn = ln.cl * CQ[q] - ln.sl * SQ[q];
    const float sn = ln.sl * CQ[q] + ln.cl * SQ[q];
    const float son = ln.so * CQ[q] + ln.co * SQ[q];   // sin(pi(2n+1)/2048)
    float dr = 0.0f, di = 0.0f;
    if (n >= lo) {
      const int idx = 2 * n + off - 1024;
      const float2 xv = *(const float2*)&xs[idx];
      dr = ws * (1.0f - cheb<L>(sn)) * xv.x;           // cos at even sample = sin(pi n/1024)
      di = ws * (1.0f - cheb<L>(son)) * xv.y;
    }
    const float2 W = make_float2(cn, -sn);             // exp(-pi i n/1024)
    const float2 W2 = csq(W);
    const float2 W3 = cmul(W, W2);
    const int p0 = SW(n), p1 = SW(n + 512), p2 = SW(n + 1024), p3 = SW(n + 1536);
    re[p0] = dr;                       im[p0] = di;
    re[p1] = -di * W.x - dr * W.y;     im[p1] = -di * W.y + dr * W.x;     // (i d) W
    re[p2] = -(dr * W2.x - di * W2.y); im[p2] = -(dr * W2.y + di * W2.x); // -d W^2
    re[p3] =  di * W3.x + dr * W3.y;   im[p3] =  di * W3.y - dr * W3.x;   // (-i d) W^3
  }
}

__device__ __forceinline__ void bfly4(float* __restrict__ re, float* __restrict__ im,
                                      int i0, int i1, int i2, int i3,
                                      float2 W, float2 W2, float2 W3) {
  float ar = re[i0], ai = im[i0];
  float br = re[i1], bi = im[i1];
  float cr = re[i2], ci = im[i2];
  float dr = re[i3], di = im[i3];
  float t0r = ar + cr, t0i = ai + ci;
  float t1r = ar - cr, t1i = ai - ci;
  float t2r = br + dr, t2i = bi + di;
  float t3r = br - dr, t3i = bi - di;
  re[i0] = t0r + t2r; im[i0] = t0i + t2i;
  float y1r = t1r + t3i, y1i = t1i - t3r;
  re[i1] = y1r * W.x - y1i * W.y;  im[i1] = y1r * W.y + y1i * W.x;
  float y2r = t0r - t2r, y2i = t0i - t2i;
  re[i2] = y2r * W2.x - y2i * W2.y; im[i2] = y2r * W2.y + y2i * W2.x;
  float y3r = t1r - t3i, y3i = t1i + t3r;
  re[i3] = y3r * W3.x - y3i * W3.y; im[i3] = y3r * W3.y + y3i * W3.x;
}

// Wave-internal LDS ordering (lockstep wave64 + lgkmcnt drain) — proven r12.
__device__ __forceinline__ void wfence() { __threadfence_block(); }

// Remaining 4 radix-4 stages, entirely within one wave on its own z-slot.
__device__ __forceinline__ void stages(float* __restrict__ re, float* __restrict__ im,
                                       const Lane& ln) {
  const int lam = threadIdx.x & 63;
  wfence();
  { // m=128
    const float2 Wa = ln.A7, Wb = cmul(Wa, make_float2(R2C, -R2C));
    const float2 Wa2 = csq(Wa), Wb2 = csq(Wb);
    const float2 Wa3 = cmul(Wa, Wa2), Wb3 = cmul(Wb, Wb2);
    #pragma unroll
    for (int q = 0; q < 8; ++q) {
      const int j = lam + 64 * q;
      const int base = ((j >> 7) << 9) | (j & 127);
      if (q & 1) bfly4(re, im, SW(base), SW(base + 128), SW(base + 256), SW(base + 384), Wb, Wb2, Wb3);
      else       bfly4(re, im, SW(base), SW(base + 128), SW(base + 256), SW(base + 384), Wa, Wa2, Wa3);
    }
  }
  wfence();
  { // m=32
    const float2 W = ln.T5, W2 = csq(W), W3 = cmul(W, W2);
    #pragma unroll
    for (int q = 0; q < 8; ++q) {
      const int j = lam + 64 * q;
      const int base = ((j >> 5) << 7) | (j & 31);
      bfly4(re, im, SW(base), SW(base + 32), SW(base + 64), SW(base + 96), W, W2, W3);
    }
  }
  wfence();
  { // m=8
    const float2 W = ln.T3, W2 = csq(W), W3 = cmul(W, W2);
    #pragma unroll
    for (int q = 0; q < 8; ++q) {
      const int j = lam + 64 * q;
      const int base = ((j >> 3) << 5) | (j & 7);
      bfly4(re, im, SW(base), SW(base + 8), SW(base + 16), SW(base + 24), W, W2, W3);
    }
  }
  wfence();
  { // m=2 (constant twiddles)
    const bool o = (lam & 1);
    const float2 W  = o ? make_float2(R2C, -R2C)   : make_float2(1.0f, 0.0f);
    const float2 W2 = o ? make_float2(0.0f, -1.0f) : make_float2(1.0f, 0.0f);
    const float2 W3 = o ? make_float2(-R2C, -R2C)  : make_float2(1.0f, 0.0f);
    #pragma unroll
    for (int q = 0; q < 8; ++q) {
      const int j = lam + 64 * q;
      const int base = ((j >> 1) << 3) | (j & 1);
      bfly4(re, im, SW(base), SW(base + 2), SW(base + 4), SW(base + 6), W, W2, W3);
    }
  }
  wfence();
}

// ---- r9-proven shared-read pair unpack ----
__device__ __forceinline__ void pair_powers(const float* __restrict__ re,
                                            const float* __restrict__ im,
                                            int kp, float2 U, float& pp, float& pm) {
  const int k1 = kp & (NC - 1);
  const int k2 = (NC - kp) & (NC - 1);
  const int q1 = SW(posrev10(k1 & 1023));
  const int q2 = SW(posrev10(k2 & 1023));
  const float s1 = (k1 & 1024) ? -1.0f : 1.0f;
  const float s2 = (k2 & 1024) ? -1.0f : 1.0f;
  const float2 vr1 = *(const float2*)&re[q1 & ~1];
  const float2 vi1 = *(const float2*)&im[q1 & ~1];
  const float2 vr2 = *(const float2*)&re[q2 & ~1];
  const float2 vi2 = *(const float2*)&im[q2 & ~1];
  const bool o1 = (q1 & 1), o2 = (q2 & 1);
  const float zkr = o1 ? (vr1.y + s1 * vr1.x) : (vr1.x + s1 * vr1.y);
  const float zki = o1 ? (vi1.y + s1 * vi1.x) : (vi1.x + s1 * vi1.y);
  const float zmr = o2 ? (vr2.y + s2 * vr2.x) : (vr2.x + s2 * vr2.y);
  const float zmi = o2 ? (vi2.y + s2 * vi2.x) : (vi2.x + s2 * vi2.y);
  const float Ex = 0.5f * (zkr + zmr), Ey = 0.5f * (zki - zmi);
  const float Ox = 0.5f * (zki + zmi), Oy = -0.5f * (zkr - zmr);
  const float Vx = U.x * Ox - U.y * Oy, Vy = U.x * Oy + U.y * Ox;
  const float ax = Ex + Vx, ay = Ey + Vy;
  const float bx = Ex - Vx, by = Ey - Vy;
  pp = ax * ax + ay * ay;
  pm = bx * bx + by * by;
}

// Thread t owns bands {t, 2048-t, 512+t, 1536-t, (1024 if t==0)}; 32B per band.
__device__ __forceinline__ void store_all(const __half2 (&oh)[4][5], float* __restrict__ outb) {
  const int t = threadIdx.x;
  #pragma unroll
  for (int sl = 0; sl < 5; ++sl) {
    if (sl < 4 || t == 0) {
      const int band = (sl == 0) ? t : (sl == 1) ? 2048 - t
                     : (sl == 2) ? 512 + t : (sl == 3) ? 1536 - t : 1024;
      float* bp = outb + (size_t)band * 8;
      *(float4*)(bp)     = make_float4(__half2float(oh[0][sl].x), __half2float(oh[0][sl].y),
                                       __half2float(oh[1][sl].x), __half2float(oh[1][sl].y));
      *(float4*)(bp + 4) = make_float4(__half2float(oh[2][sl].x), __half2float(oh[2][sl].y),
                                       __half2float(oh[3][sl].x), __half2float(oh[3][sl].y));
    }
  }
}

__global__ __launch_bounds__(THREADS) void spec_kernel(const float* __restrict__ x,
                                                       float* __restrict__ out) {
  __shared__ Smem sm;
  const int tid = threadIdx.x;
  const int lam = tid & 63;
  const int w = tid >> 6;
  const int b = blockIdx.x;
  for (int i = tid; i < BUF; i += THREADS) sm.xs[i] = x[(size_t)b * BUF + i];
  Lane ln;
  {
    float sn, cs;
    sincospif((float)lam * (1.0f / 1024.0f), &sn, &cs);           ln.cl = cs; ln.sl = sn;
    sincospif((float)(2 * lam + 1) * (1.0f / 2048.0f), &sn, &cs); ln.co = cs; ln.so = sn;
    sincospif((float)lam * (1.0f / 256.0f), &sn, &cs);            ln.A7 = make_float2(cs, -sn);
    sincospif((float)(lam & 31) * (1.0f / 64.0f), &sn, &cs);      ln.T5 = make_float2(cs, -sn);
    sincospif((float)(lam & 7) * (1.0f / 16.0f), &sn, &cs);       ln.T3 = make_float2(cs, -sn);
    sincospif((float)tid * (1.0f / 2048.0f), &sn, &cs);           ln.Ub = make_float2(cs, -sn);
  }
  const float2 U1 = cmul(ln.Ub, make_float2(R2C, -R2C));
  float* outb = out + (size_t)b * (NBANDS * 8);
  float s2[4][5];      // min(l0, l1_{j>>1}, l2_j) per band-slot; persists SP1->SP2
  __half2 oh[4][5];    // dB output columns, f16-packed

  __syncthreads();     // xs ready

  // ---- Super-pass 1 FFTs: z[0..7] = {l0, l1_0, l1_1, l2_0..l2_3, l3_0} ----
  if      (w == 0) { fs1<0>(sm.zre[0], sm.zim[0], sm.xs, ln, 1024); stages(sm.zre[0], sm.zim[0], ln); }
  else if (w == 1) { fs1<1>(sm.zre[1], sm.zim[1], sm.xs, ln,  512); stages(sm.zre[1], sm.zim[1], ln); }
  else if (w == 2) { fs1<1>(sm.zre[2], sm.zim[2], sm.xs, ln, 1024); stages(sm.zre[2], sm.zim[2], ln); }
  else if (w == 3) { fs1<2>(sm.zre[3], sm.zim[3], sm.xs, ln,  256); stages(sm.zre[3], sm.zim[3], ln); }
  else if (w == 4) { fs1<2>(sm.zre[4], sm.zim[4], sm.xs, ln,  512); stages(sm.zre[4], sm.zim[4], ln); }
  else if (w == 5) { fs1<2>(sm.zre[5], sm.zim[5], sm.xs, ln,  768); stages(sm.zre[5], sm.zim[5], ln); }
  else if (w == 6) { fs1<2>(sm.zre[6], sm.zim[6], sm.xs, ln, 1024); stages(sm.zre[6], sm.zim[6], ln); }
  else             { fs1<3>(sm.zre[7], sm.zim[7], sm.xs, ln,  128); stages(sm.zre[7], sm.zim[7], ln); }
  __syncthreads();

  // ---- Super-pass 1 unpack: build s2[4] and o0 in registers ----
  #pragma unroll
  for (int sp = 0; sp < 2; ++sp) {
    const int kp = sp ? 512 + tid : tid;
    const float2 U = sp ? U1 : ln.Ub;
    const int sA = 2 * sp, sB = sA + 1;
    float pl0a, pl0b, pa, pb;
    pair_powers(sm.zre[0], sm.zim[0], kp, U, pl0a, pl0b);                 // l0
    pair_powers(sm.zre[1], sm.zim[1], kp, U, pa, pb);                     // l1_0
    const float a0 = fminf(pl0a, pa), a1 = fminf(pl0b, pb);
    pair_powers(sm.zre[2], sm.zim[2], kp, U, pa, pb);                     // l1_1
    const float b0 = fminf(pl0a, pa), b1 = fminf(pl0b, pb);
    pair_powers(sm.zre[3], sm.zim[3], kp, U, pa, pb);                     // l2_0
    s2[0][sA] = fminf(fminf(a0, pa), 1.0e6f); s2[0][sB] = fminf(fminf(a1, pb), 1.0e6f);
    pair_powers(sm.zre[4], sm.zim[4], kp, U, pa, pb);                     // l2_1
    s2[1][sA] = fminf(fminf(a0, pa), 1.0e6f); s2[1][sB] = fminf(fminf(a1, pb), 1.0e6f);
    pair_powers(sm.zre[5], sm.zim[5], kp, U, pa, pb);                     // l2_2
    s2[2][sA] = fminf(fminf(b0, pa), 1.0e6f); s2[2][sB] = fminf(fminf(b1, pb), 1.0e6f);
    pair_powers(sm.zre[6], sm.zim[6], kp, U, pa, pb);                     // l2_3
    s2[3][sA] = fminf(fminf(b0, pa), 1.0e6f); s2[3][sB] = fminf(fminf(b1, pb), 1.0e6f);
    pair_powers(sm.zre[7], sm.zim[7], kp, U, pa, pb);                     // l3_0
    oh[0][sA].x = __float2half_rn(dbv(fminf(s2[0][sA], pa)));
    oh[0][sB].x = __float2half_rn(dbv(fminf(s2[0][sB], pb)));
  }
  if (tid == 0) {      // band 1024: Z[1024] = D[0]-D[1]
    float p[8];
    #pragma unroll
    for (int f = 0; f < 8; ++f) {
      const float zr = sm.zre[f][0] - sm.zre[f][1];
      const float zi = sm.zim[f][0] - sm.zim[f][1];
      p[f] = zr * zr + zi * zi;
    }
    const float a = fminf(p[0], p[1]), bb = fminf(p[0], p[2]);
    s2[0][4] = fminf(fminf(a, p[3]), 1.0e6f);
    s2[1][4] = fminf(fminf(a, p[4]), 1.0e6f);
    s2[2][4] = fminf(fminf(bb, p[5]), 1.0e6f);
    s2[3][4] = fminf(fminf(bb, p[6]), 1.0e6f);
    oh[0][4].x = __float2half_rn(dbv(fminf(s2[0][4], p[7])));
  }
  __syncthreads();

  // ---- Super-pass 2 FFTs: z[0..6] = {l3_1..l3_7} ----
  if (w < 7) { fs1<3>(sm.zre[w], sm.zim[w], sm.xs, ln, 256 + 128 * w); stages(sm.zre[w], sm.zim[w], ln); }
  __syncthreads();

  // ---- Super-pass 2 unpack: o1..o7 = dB(min(s2_{col>>1}, l3_col)) ----
  #pragma unroll
  for (int sp = 0; sp < 2; ++sp) {
    const int kp = sp ? 512 + tid : tid;
    const float2 U = sp ? U1 : ln.Ub;
    const int sA = 2 * sp, sB = sA + 1;
    #pragma unroll
    for (int fi = 0; fi < 7; ++fi) {
      const int col = fi + 1, nd = col >> 1;
      float pa, pb;
      pair_powers(sm.zre[fi], sm.zim[fi], kp, U, pa, pb);
      const __half hA = __float2half_rn(dbv(fminf(s2[nd][sA], pa)));
      const __half hB = __float2half_rn(dbv(fminf(s2[nd][sB], pb)));
      if (col & 1) { oh[col >> 1][sA].y = hA; oh[col >> 1][sB].y = hB; }
      else         { oh[col >> 1][sA].x = hA; oh[col >> 1][sB].x = hB; }
    }
  }
  if (tid == 0) {
    #pragma unroll
    for (int fi = 0; fi < 7; ++fi) {
      const int col = fi + 1, nd = col >> 1;
      const float zr = sm.zre[fi][0] - sm.zre[fi][1];
      const float zi = sm.zim[fi][0] - sm.zim[fi][1];
      const __half h = __float2half_rn(dbv(fminf(s2[nd][4], zr * zr + zi * zi)));
      if (col & 1) oh[col >> 1][4].y = h;
      else         oh[col >> 1][4].x = h;
    }
  }

  store_all(oh, outb);
}

extern "C" void kernel_launch(void* const* d_in, const int* in_sizes, int n_in,
                              void* d_out, int out_size, void* d_ws, size_t ws_size,
                              hipStream_t stream) {
  const float* x = (const float*)d_in[0];
  float* out = (float*)d_out;
  const int B = in_sizes[0] / BUF;
  hipLaunchKernelGGL(spec_kernel, dim3(B), dim3(THREADS), 0, stream, x, out);
}

// Round 19
// 107.474 us; speedup vs baseline: 4.5449x; 1.0480x over previous
//
#include <hip/hip_runtime.h>
#include <hip/hip_fp16.h>
#include <math.h>

#define NBANDS 2049
#define NF 4096      // real frame size
#define NC 2048      // complex FFT size (rfft via packed complex)
#define BUF 1024     // input samples per batch row
#define THREADS 512
#define R2C 0.70710678118654752f

// LDS bank swizzle (empirically proven r6/r9: 1.9M conflicts)
__device__ __forceinline__ int SW(int i) { return i ^ (i >> 2) ^ (i >> 6); }

// digit-reversed position after 5 radix-4 stages (final radix-2 folded out);
// output is always even
__device__ __forceinline__ int posrev10(int j) {
  return ((j & 3) << 9) | (((j >> 2) & 3) << 7) | (((j >> 4) & 3) << 5) |
         (((j >> 6) & 3) << 3) | (((j >> 8) & 3) << 1);
}

struct Smem {
  alignas(16) float xs[BUF];                 // 4 KB
  alignas(16) float zre[3][NC];              // 24 KB
  alignas(16) float zim[3][NC];              // 24 KB
};                                           // 52.5 KB -> 2 blocks/CU

struct State {
  float2 W[5];                   // per-thread stage twiddles
  float2 Ub;                     // exp(-pi*i*tid/2048)
  float2 U1;                     // Ub * exp(-i*pi/4)
  float so;                      // sin(pi*(2*tid+1)/2048) (odd window base)
  float s1a[5], s1b[5];          // running mins after lvl1 (two subtrees)
  float s2a[5], s2b[5];          // running mins after lvl2 (two live nodes)
  __half2 oh[4][5];              // dB output columns, f16-packed in registers
};

__device__ __forceinline__ float2 cmul(float2 a, float2 b) {
  return make_float2(a.x * b.x - a.y * b.y, a.x * b.y + a.y * b.x);
}

// Wave-internal LDS ordering (lockstep wave64 + lgkmcnt drain) — proven r12/r18.
__device__ __forceinline__ void wfence() { __threadfence_block(); }

// Chebyshev cos-doubling: cos(t) -> cos(2^L * t)
template <int L>
__device__ __forceinline__ float cheb(float c) {
  #pragma unroll
  for (int i = 0; i < L; ++i) c = 2.0f * c * c - 1.0f;
  return c;
}

// Fused pack + pruned first radix-4 stage (span 512): only tap3 nonzero.
// y = {d, i*d*W, -d*W^2, -i*d*W^3}, d = windowed sample pair from xs.
template <int L>
__device__ __forceinline__ void fused_s1(float* __restrict__ re, float* __restrict__ im,
                                         const Smem& sm, const State& st, int off) {
  const int n = threadIdx.x;
  constexpr int M = NF >> L;
  constexpr float ws = (float)(1 << L) * (0.5f / 1024.0f);
  const int lo = 512 - (min(off, M) >> 1);
  float dr = 0.0f, di = 0.0f;
  if (n >= lo) {
    const int idx = 2 * n + off - 1024;          // even, in [0, off)
    const float2 xv = *(const float2*)&sm.xs[idx];
    const float cE = cheb<L>(-st.W[0].y);        // cos at even sample
    const float cO = cheb<L>(st.so);             // cos at odd sample
    dr = ws * (1.0f - cE) * xv.x;
    di = ws * (1.0f - cO) * xv.y;
  }
  const float2 W = st.W[0];
  const float2 W2 = make_float2(W.x * W.x - W.y * W.y, 2.0f * W.x * W.y);
  const float2 W3 = cmul(W, W2);
  const int p0 = SW(n), p1 = SW(n + 512), p2 = SW(n + 1024), p3 = SW(n + 1536);
  re[p0] = dr;                       im[p0] = di;
  re[p1] = -di * W.x - dr * W.y;     im[p1] = -di * W.y + dr * W.x;     // (i d) W
  re[p2] = -(dr * W2.x - di * W2.y); im[p2] = -(dr * W2.y + di * W2.x); // -d W^2
  re[p3] =  di * W3.x + dr * W3.y;   im[p3] =  di * W3.y - dr * W3.x;   // (-i d) W^3
}

__device__ __forceinline__ void bfly4(float* __restrict__ re, float* __restrict__ im,
                                      int i0, int i1, int i2, int i3,
                                      float2 W, float2 W2, float2 W3) {
  float ar = re[i0], ai = im[i0];
  float br = re[i1], bi = im[i1];
  float cr = re[i2], ci = im[i2];
  float dr = re[i3], di = im[i3];
  float t0r = ar + cr, t0i = ai + ci;
  float t1r = ar - cr, t1i = ai - ci;
  float t2r = br + dr, t2i = bi + di;
  float t3r = br - dr, t3i = bi - di;
  re[i0] = t0r + t2r; im[i0] = t0i + t2i;
  float y1r = t1r + t3i, y1i = t1i - t3r;                  // (t1 - i*t3)
  re[i1] = y1r * W.x - y1i * W.y;  im[i1] = y1r * W.y + y1i * W.x;
  float y2r = t0r - t2r, y2i = t0i - t2i;
  re[i2] = y2r * W2.x - y2i * W2.y; im[i2] = y2r * W2.y + y2i * W2.x;
  float y3r = t1r - t3i, y3i = t1i + t3r;                  // (t1 + i*t3)
  re[i3] = y3r * W3.x - y3i * W3.y; im[i3] = y3r * W3.y + y3i * W3.x;
}

template <int LM, int NFR>
__device__ __forceinline__ void radix4p(Smem& sm, float2 W) {
  const int j = threadIdx.x;
  const int m = 1 << LM;
  const int base = ((j >> LM) << (LM + 2)) | (j & (m - 1));
  const int i0 = SW(base), i1 = SW(base + m), i2 = SW(base + 2 * m), i3 = SW(base + 3 * m);
  float2 W2 = make_float2(W.x * W.x - W.y * W.y, 2.0f * W.x * W.y);
  float2 W3 = cmul(W, W2);
  #pragma unroll
  for (int f = 0; f < NFR; ++f)
    bfly4(sm.zre[f], sm.zim[f], i0, i1, i2, i3, W, W2, W3);
}

// Shared-read pair unpack: bins kp and 2048-kp read the same Z values.
// {q, q^1} is an adjacent aligned float pair -> one b64 LDS read each.
__device__ __forceinline__ void pair_powers(const float* __restrict__ re,
                                            const float* __restrict__ im,
                                            int kp, float2 U, float& pp, float& pm) {
  const int k1 = kp & (NC - 1);
  const int k2 = (NC - kp) & (NC - 1);
  const int q1 = SW(posrev10(k1 & 1023));
  const int q2 = SW(posrev10(k2 & 1023));
  const float s1 = (k1 & 1024) ? -1.0f : 1.0f;
  const float s2 = (k2 & 1024) ? -1.0f : 1.0f;
  const float2 vr1 = *(const float2*)&re[q1 & ~1];
  const float2 vi1 = *(const float2*)&im[q1 & ~1];
  const float2 vr2 = *(const float2*)&re[q2 & ~1];
  const float2 vi2 = *(const float2*)&im[q2 & ~1];
  const bool o1 = (q1 & 1), o2 = (q2 & 1);
  const float zkr = o1 ? (vr1.y + s1 * vr1.x) : (vr1.x + s1 * vr1.y);
  const float zki = o1 ? (vi1.y + s1 * vi1.x) : (vi1.x + s1 * vi1.y);
  const float zmr = o2 ? (vr2.y + s2 * vr2.x) : (vr2.x + s2 * vr2.y);
  const float zmi = o2 ? (vi2.y + s2 * vi2.x) : (vi2.x + s2 * vi2.y);
  const float Ex = 0.5f * (zkr + zmr), Ey = 0.5f * (zki - zmi);
  const float Ox = 0.5f * (zki + zmi), Oy = -0.5f * (zkr - zmr);
  const float Vx = U.x * Ox - U.y * Oy, Vy = U.x * Oy + U.y * Ox;
  const float ax = Ex + Vx, ay = Ey + Vy;
  const float bx = Ex - Vx, by = Ey - Vy;
  pp = ax * ax + ay * ay;
  pm = bx * bx + by * by;
}

// ACT: 0 s1a=min(p,1e6); 1 s1b=min(p,1e6); 2 lvl0 fold into s1a&s1b;
//      3 s2a=min(s1a,p); 4 s2b=min(s1a,p); 5 s2a=min(s1b,p); 6 s2b=min(s1b,p);
//      7 o[COL]=dB(min(s2a,p)); 8 o[COL]=dB(min(s2b,p))
template <int ACT, int COL, int SLOT>
__device__ __forceinline__ void act(State& st, float p) {
  if constexpr (ACT == 0)      st.s1a[SLOT] = fminf(p, 1.0e6f);
  else if constexpr (ACT == 1) st.s1b[SLOT] = fminf(p, 1.0e6f);
  else if constexpr (ACT == 2) { st.s1a[SLOT] = fminf(st.s1a[SLOT], p); st.s1b[SLOT] = fminf(st.s1b[SLOT], p); }
  else if constexpr (ACT == 3) st.s2a[SLOT] = fminf(st.s1a[SLOT], p);
  else if constexpr (ACT == 4) st.s2b[SLOT] = fminf(st.s1a[SLOT], p);
  else if constexpr (ACT == 5) st.s2a[SLOT] = fminf(st.s1b[SLOT], p);
  else if constexpr (ACT == 6) st.s2b[SLOT] = fminf(st.s1b[SLOT], p);
  else {
    const float base = (ACT == 7) ? st.s2a[SLOT] : st.s2b[SLOT];
    const float db = 10.0f * log10f(fmaxf(fminf(base, p), 1.0e-10f));
    if constexpr (COL & 1) st.oh[COL >> 1][SLOT].y = __float2half_rn(db);
    else                   st.oh[COL >> 1][SLOT].x = __float2half_rn(db);
  }
}

template <int ACT, int COL>
__device__ __forceinline__ void unpack_frame(const float* __restrict__ re,
                                             const float* __restrict__ im,
                                             State& st) {
  const int t = threadIdx.x;
  float pp, pm;
  pair_powers(re, im, t, st.Ub, pp, pm);
  act<ACT, COL, 0>(st, pp);
  act<ACT, COL, 1>(st, pm);
  pair_powers(re, im, 512 + t, st.U1, pp, pm);
  act<ACT, COL, 2>(st, pp);
  act<ACT, COL, 3>(st, pm);
  if (t == 0) {
    // bin 1024: Z[1024] = D[0] - D[1]
    const float zr = re[0] - re[1];
    const float zi = im[0] - im[1];
    act<ACT, COL, 4>(st, zr * zr + zi * zi);
  }
}

// One pass = three windowed frames FFT'd together, unpacked, min-chain applied.
// Barrier analysis: fs1 (m=512) -> r<7> (m=128) and r<7> -> r<5> are cross-wave.
// Stages m=32 -> m=8 -> m=2 are wave-local: thread j=64w+lam touches only
// logical slice [256w, 256w+256) in all three (base=((j>>LM)<<(LM+2))|(j&(m-1))).
// SW is a fixed bijection, so dependencies stay wave-internal -> wfence suffices.
template <int LA, int AA, int CA, int LB, int AB, int CB, int LC, int AC, int CC, int NFR>
__device__ __forceinline__ void pass(Smem& sm, State& st, int offA, int offB, int offC) {
  __syncthreads();                          // prior pass done reading z arrays
  fused_s1<LA>(sm.zre[0], sm.zim[0], sm, st, offA);
  if constexpr (NFR >= 2) fused_s1<LB>(sm.zre[1], sm.zim[1], sm, st, offB);
  if constexpr (NFR >= 3) fused_s1<LC>(sm.zre[2], sm.zim[2], sm, st, offC);
  __syncthreads(); radix4p<7, NFR>(sm, st.W[1]);
  __syncthreads(); radix4p<5, NFR>(sm, st.W[2]);
  wfence();        radix4p<3, NFR>(sm, st.W[3]);
  wfence();        radix4p<1, NFR>(sm, st.W[4]);
  __syncthreads();
  unpack_frame<AA, CA>(sm.zre[0], sm.zim[0], st);
  if constexpr (NFR >= 2) unpack_frame<AB, CB>(sm.zre[1], sm.zim[1], st);
  if constexpr (NFR >= 3) unpack_frame<AC, CC>(sm.zre[2], sm.zim[2], st);
}

// Thread t owns bands {t, 2048-t, 512+t, 1536-t, (1024 if t==0)}; 32B per band.
__device__ __forceinline__ void store_all(const State& st, float* __restrict__ outb) {
  const int t = threadIdx.x;
  #pragma unroll
  for (int sl = 0; sl < 5; ++sl) {
    if (sl < 4 || t == 0) {
      const int band = (sl == 0) ? t : (sl == 1) ? 2048 - t
                     : (sl == 2) ? 512 + t : (sl == 3) ? 1536 - t : 1024;
      float* bp = outb + (size_t)band * 8;
      *(float4*)(bp)     = make_float4(__half2float(st.oh[0][sl].x), __half2float(st.oh[0][sl].y),
                                       __half2float(st.oh[1][sl].x), __half2float(st.oh[1][sl].y));
      *(float4*)(bp + 4) = make_float4(__half2float(st.oh[2][sl].x), __half2float(st.oh[2][sl].y),
                                       __half2float(st.oh[3][sl].x), __half2float(st.oh[3][sl].y));
    }
  }
}

__global__ __launch_bounds__(THREADS, 2) void spec_kernel(const float* __restrict__ x,
                                                          float* __restrict__ out) {
  __shared__ Smem sm;
  State st;
  const int tid = threadIdx.x;
  const int b = blockIdx.x;
  const float* xb = x + (size_t)b * BUF;
  #pragma unroll
  for (int i = tid; i < BUF; i += THREADS) sm.xs[i] = xb[i];
  {
    float sn, cs;
    sincospif((float)tid * (1.0f / 1024.0f), &sn, &cs);         st.W[0] = make_float2(cs, -sn);
    sincospif((float)(tid & 127) * (1.0f / 256.0f), &sn, &cs);  st.W[1] = make_float2(cs, -sn);
    sincospif((float)(tid & 31) * (1.0f / 64.0f), &sn, &cs);    st.W[2] = make_float2(cs, -sn);
    sincospif((float)(tid & 7) * (1.0f / 16.0f), &sn, &cs);     st.W[3] = make_float2(cs, -sn);
    st.W[4] = (tid & 1) ? make_float2(R2C, -R2C) : make_float2(1.0f, 0.0f);
    sincospif((float)tid * (1.0f / 2048.0f), &sn, &cs);         st.Ub = make_float2(cs, -sn);
    st.U1 = cmul(st.Ub, make_float2(R2C, -R2C));
    sincospif((float)(2 * tid + 1) * (1.0f / 2048.0f), &sn, &cs); st.so = sn;
  }
  float* outb = out + (size_t)b * (NBANDS * 8);

  // Frames: lvl0 off=1024; lvl1 off=512*(i+1); lvl2 off=256*(i+1); lvl3 off=128*(i+1)
  // 15 frames in 5 passes of 3 (schedule verified r9):
  pass<1, 0, 0,  1, 1, 0,  0, 2, 0, 3>(sm, st, 512, 1024, 1024);  // s1a=l1_0; s1b=l1_1; fold l0
  pass<2, 3, 0,  2, 4, 0,  3, 7, 0, 3>(sm, st, 256, 512, 128);    // s2a=min(s1a,l2_0); s2b=min(s1a,l2_1); o0
  pass<3, 7, 1,  3, 8, 2,  3, 8, 3, 3>(sm, st, 256, 384, 512);    // o1(s2a); o2(s2b); o3(s2b)
  pass<2, 5, 0,  2, 6, 0,  3, 7, 4, 3>(sm, st, 768, 1024, 640);   // s2a=min(s1b,l2_2); s2b=min(s1b,l2_3); o4
  pass<3, 7, 5,  3, 8, 6,  3, 8, 7, 3>(sm, st, 768, 896, 1024);   // o5(s2a); o6(s2b); o7(s2b)
  store_all(st, outb);
}

extern "C" void kernel_launch(void* const* d_in, const int* in_sizes, int n_in,
                              void* d_out, int out_size, void* d_ws, size_t ws_size,
                              hipStream_t stream) {
  const float* x = (const float*)d_in[0];
  float* out = (float*)d_out;
  const int B = in_sizes[0] / BUF;
  hipLaunchKernelGGL(spec_kernel, dim3(B), dim3(THREADS), 0, stream, x, out);
}